// Round 7
// baseline (198.646 us; speedup 1.0000x reference)
//
#include <hip/hip_runtime.h>
#include <math.h>

#define BATCH   4
#define S_LEN   2048
#define DMODEL  512
#define NHEADS  8
#define DHEAD   64
#define M_TOT   8192
#define ATT_SCALE 0.04419417382415922f   // 1/sqrt(512)
#define QSCALE (ATT_SCALE * 1.44269504088896f)  // fold log2(e): exp2 in softmax

using short8  = __attribute__((ext_vector_type(8))) short;
using floatx4 = __attribute__((ext_vector_type(4))) float;

// fp32 -> bf16 RNE
__device__ __forceinline__ ushort f2bf(float f) {
    union { float f; unsigned u; } x; x.f = f;
    unsigned u = x.u + 0x7FFFu + ((x.u >> 16) & 1u);
    return (ushort)(u >> 16);
}
__device__ __forceinline__ unsigned pk2(float a, float b) {
    return (unsigned)f2bf(a) | ((unsigned)f2bf(b) << 16);
}
// fp32x2 -> packed bf16x2, round-half-up — hot-loop use
__device__ __forceinline__ unsigned pkr2(float a, float b) {
    unsigned ua = __float_as_uint(a) + 0x8000u;
    unsigned ub = __float_as_uint(b) + 0x8000u;
    return __builtin_amdgcn_perm(ub, ua, 0x07060302u);
}
// async global->LDS, 16B per lane; lds dst = wave-uniform base + lane*16
__device__ __forceinline__ void gload16(const ushort* g, ushort* l) {
    __builtin_amdgcn_global_load_lds(
        (const __attribute__((address_space(1))) void*)g,
        (__attribute__((address_space(3))) void*)l, 16, 0, 0);
}

// ---------------------------------------------------------------------------
// Preprocess (merged): blocks [0,4096) convert x fp32->bf16; blocks
// [4096,4352) transpose the four W's into WT[p][n][k] bf16.
// ---------------------------------------------------------------------------
__global__ __launch_bounds__(256) void prep(
    const float* __restrict__ x,
    const float* __restrict__ Wq, const float* __restrict__ Wk,
    const float* __restrict__ Wv, const float* __restrict__ Wo,
    ushort* __restrict__ xb, ushort* __restrict__ WT)
{
    const int bid = blockIdx.x;
    if (bid < 4096) {
        const int i = (bid * 256 + threadIdx.x) * 4;
        float4 f = *(const float4*)(x + i);
        uint2 o; o.x = pk2(f.x, f.y); o.y = pk2(f.z, f.w);
        *(uint2*)(xb + i) = o;
    } else {
        const int rb = bid - 4096;
        const int p  = rb >> 6;
        const int rem = rb & 63;
        const int n  = (rem >> 5) * 256 + threadIdx.x;
        const int k0 = (rem & 31) * 16;
        const float* W = (p == 0) ? Wq : (p == 1) ? Wk : (p == 2) ? Wv : Wo;
        unsigned u[8];
        #pragma unroll
        for (int j = 0; j < 8; ++j) {
            float a = W[(k0 + 2 * j)     * DMODEL + n];
            float b = W[(k0 + 2 * j + 1) * DMODEL + n];
            u[j] = pk2(a, b);
        }
        ushort* dst = WT + ((size_t)p * DMODEL + n) * DMODEL + k0;
        *(uint4*)dst       = *(uint4*)&u[0];
        *(uint4*)(dst + 8) = *(uint4*)&u[4];
    }
}

// ---------------------------------------------------------------------------
// Kernel 1: fused QKV projection, 128x128 tile, BK=32.
// Staging via global_load_lds (16B/lane DMA) into permuted LDS layout
// [kquad][row][8] (granule = kquad*128+row at offset granule*16B):
// fragment ds_read_b128 at &As[(kquad*128 + row)*8] is conflict-free.
// Q pre-scaled by QSCALE.  V (p==2) exits via LDS transpose -> b128 stores.
// ---------------------------------------------------------------------------
__global__ __launch_bounds__(256) void qkv_gemm(
    const ushort* __restrict__ xb, const ushort* __restrict__ WT,
    const float* __restrict__ bq, const float* __restrict__ bk, const float* __restrict__ bv,
    ushort* __restrict__ q, ushort* __restrict__ k, ushort* __restrict__ vT)
{
    __shared__ ushort SMEM[128 * 136];       // 34.8 KB (CT overlay needs it)
    ushort* As = SMEM;                       // 8 KB  (4096 ushorts)
    ushort* Bs = SMEM + 4096;                // 8 KB
    ushort (*CT)[136] = (ushort(*)[136])SMEM;

    const int tid = threadIdx.x;
    const int wv  = tid >> 6, lane = tid & 63, l16 = lane & 15, quad = lane >> 4;
    const int m0  = blockIdx.x * 128;
    const int ng0 = blockIdx.y * 128;
    const int p   = ng0 >> 9;
    const int n0  = ng0 & 511;
    const ushort* Wp  = WT + (size_t)p * DMODEL * DMODEL + (size_t)n0 * DMODEL;
    const float* bias = (p == 0) ? bq : (p == 1) ? bk : bv;
    const float scl   = (p == 0) ? QSCALE : 1.0f;

    const int wm = (wv & 1) * 64, wn = (wv >> 1) * 64;
    floatx4 acc[4][4] = {};

    // DMA granule mapping for this thread's two calls (c=0,1):
    //   g64 = wv*2+c; kquad = g64>>1; row = (g64&1)*64 + lane
    for (int k0 = 0; k0 < DMODEL; k0 += 32) {
        #pragma unroll
        for (int c = 0; c < 2; ++c) {
            const int g64 = wv * 2 + c;
            const int qk  = g64 >> 1;
            const int row = ((g64 & 1) << 6) + lane;
            gload16(xb + (size_t)(m0 + row) * DMODEL + k0 + qk * 8, As + g64 * 512);
            gload16(Wp + (size_t)row * DMODEL + k0 + qk * 8,        Bs + g64 * 512);
        }
        __syncthreads();

        short8 af[4], bf[4];
        #pragma unroll
        for (int i = 0; i < 4; ++i)
            af[i] = *(const short8*)(As + (size_t)(quad * 128 + wm + i * 16 + l16) * 8);
        #pragma unroll
        for (int c = 0; c < 4; ++c)
            bf[c] = *(const short8*)(Bs + (size_t)(quad * 128 + wn + c * 16 + l16) * 8);
        #pragma unroll
        for (int i = 0; i < 4; ++i)
            #pragma unroll
            for (int c = 0; c < 4; ++c)
                acc[i][c] = __builtin_amdgcn_mfma_f32_16x16x32_bf16(af[i], bf[c], acc[i][c], 0, 0, 0);
        __syncthreads();
    }

    if (p < 2) {
        #pragma unroll
        for (int c = 0; c < 4; ++c) {
            const int n = n0 + wn + c * 16 + l16;
            const float bb = bias[n];
            const int h = n >> 6, dh = n & 63;
            #pragma unroll
            for (int i = 0; i < 4; ++i)
                #pragma unroll
                for (int r = 0; r < 4; ++r) {
                    const int m = m0 + wm + i * 16 + quad * 4 + r;
                    const int b = m >> 11, s = m & 2047;
                    const ushort val = f2bf((acc[i][c][r] + bb) * scl);
                    if (p == 0) q[((size_t)(b * NHEADS + h) * S_LEN + s) * DHEAD + dh] = val;
                    else        k[((size_t)(b * NHEADS + h) * S_LEN + s) * DHEAD + dh] = val;
                }
        }
    } else {
        // V: stage C^T[n][m] in LDS (b64 packed), then coalesced b128 stores
        #pragma unroll
        for (int c = 0; c < 4; ++c) {
            const int n = wn + c * 16 + l16;
            const float bb = bias[n0 + n];
            #pragma unroll
            for (int i = 0; i < 4; ++i) {
                uint2 o;
                o.x = pk2(acc[i][c][0] + bb, acc[i][c][1] + bb);
                o.y = pk2(acc[i][c][2] + bb, acc[i][c][3] + bb);
                *(uint2*)&CT[n][wm + i * 16 + quad * 4] = o;
            }
        }
        __syncthreads();
        const int n  = tid >> 1, mh = (tid & 1) * 64;
        const int gn = n0 + n;
        const int h  = gn >> 6, dh = gn & 63;
        const int b  = m0 >> 11, sb = (m0 & 2047) + mh;
        ushort* dst = vT + ((size_t)(b * NHEADS + h) * DHEAD + dh) * S_LEN + sb;
        #pragma unroll
        for (int j = 0; j < 8; ++j)
            *(uint4*)(dst + j * 8) = *(const uint4*)&CT[n][mh + j * 8];
    }
}

// ---------------------------------------------------------------------------
// Kernel 2: flash attention, S^T = K·Q^T, SPLIT-S over blockIdx.z (unchanged).
// ---------------------------------------------------------------------------
__global__ __launch_bounds__(256, 4) void attn(
    const ushort* __restrict__ Q, const ushort* __restrict__ K,
    const ushort* __restrict__ vT, ushort* __restrict__ att,
    float* __restrict__ Opart, float* __restrict__ Lpart,
    const int KT, const int direct)
{
    __shared__ ushort Klds[64][72];
    __shared__ ushort Vt[64][72];
    __shared__ ushort Plds[128][72];

    const int tid = threadIdx.x;
    const int wv  = tid >> 6, lane = tid & 63, l16 = lane & 15, quad = lane >> 4;
    const int q0  = blockIdx.x * 128;
    const int bh  = blockIdx.y;
    const int ck  = blockIdx.z;
    const int kbase = ck * KT;
    const ushort* Qh = Q  + (size_t)bh * S_LEN * DHEAD;
    const ushort* Kh = K  + (size_t)bh * S_LEN * DHEAD;
    const ushort* Vh = vT + (size_t)bh * DHEAD * S_LEN;

    short8 qf[2][2];
    #pragma unroll
    for (int ni = 0; ni < 2; ++ni) {
        const ushort* qrow = Qh + (size_t)(q0 + wv * 32 + ni * 16 + l16) * DHEAD;
        qf[0][ni] = *(const short8*)(qrow + quad * 8);
        qf[1][ni] = *(const short8*)(qrow + 32 + quad * 8);
    }

    floatx4 oacc[4][2] = {};
    float lsum[2] = {0.f, 0.f};

    const int srow = tid >> 2, sc0 = (tid & 3) * 16;
    uint4 ka, kb, va, vb;
    {
        const ushort* Ks = Kh + (size_t)(kbase * 64 + srow) * DHEAD + sc0;
        const ushort* Vs = Vh + (size_t)srow * S_LEN + kbase * 64 + sc0;
        ka = *(const uint4*)Ks; kb = *(const uint4*)(Ks + 8);
        va = *(const uint4*)Vs; vb = *(const uint4*)(Vs + 8);
    }

    for (int kt = 0; kt < KT; ++kt) {
        *(uint4*)&Klds[srow][sc0] = ka; *(uint4*)&Klds[srow][sc0 + 8] = kb;
        *(uint4*)&Vt[srow][sc0]   = va; *(uint4*)&Vt[srow][sc0 + 8]   = vb;
        __syncthreads();

        if (kt + 1 < KT) {
            const ushort* Ks = Kh + (size_t)((kbase + kt + 1) * 64 + srow) * DHEAD + sc0;
            const ushort* Vs = Vh + (size_t)srow * S_LEN + (kbase + kt + 1) * 64 + sc0;
            ka = *(const uint4*)Ks; kb = *(const uint4*)(Ks + 8);
            va = *(const uint4*)Vs; vb = *(const uint4*)(Vs + 8);
        }

        floatx4 sc[4][2] = {};
        #pragma unroll
        for (int s = 0; s < 2; ++s)
            #pragma unroll
            for (int mi = 0; mi < 4; ++mi) {
                short8 kf = *(const short8*)&Klds[mi * 16 + l16][s * 32 + quad * 8];
                #pragma unroll
                for (int ni = 0; ni < 2; ++ni)
                    sc[mi][ni] = __builtin_amdgcn_mfma_f32_16x16x32_bf16(kf, qf[s][ni], sc[mi][ni], 0, 0, 0);
            }

        #pragma unroll
        for (int mi = 0; mi < 4; ++mi)
            #pragma unroll
            for (int ni = 0; ni < 2; ++ni) {
                const float p0 = __builtin_amdgcn_exp2f(sc[mi][ni][0]);
                const float p1 = __builtin_amdgcn_exp2f(sc[mi][ni][1]);
                const float p2 = __builtin_amdgcn_exp2f(sc[mi][ni][2]);
                const float p3 = __builtin_amdgcn_exp2f(sc[mi][ni][3]);
                lsum[ni] += (p0 + p1) + (p2 + p3);
                uint2 o; o.x = pkr2(p0, p1); o.y = pkr2(p2, p3);
                *(uint2*)&Plds[wv * 32 + ni * 16 + l16][mi * 16 + quad * 4] = o;
            }

        #pragma unroll
        for (int s = 0; s < 2; ++s) {
            short8 pf[2];
            #pragma unroll
            for (int ni = 0; ni < 2; ++ni)
                pf[ni] = *(const short8*)&Plds[wv * 32 + ni * 16 + l16][s * 32 + quad * 8];
            #pragma unroll
            for (int mi = 0; mi < 4; ++mi) {
                short8 vf = *(const short8*)&Vt[mi * 16 + l16][s * 32 + quad * 8];
                #pragma unroll
                for (int ni = 0; ni < 2; ++ni)
                    oacc[mi][ni] = __builtin_amdgcn_mfma_f32_16x16x32_bf16(vf, pf[ni], oacc[mi][ni], 0, 0, 0);
            }
        }
        __syncthreads();
    }

    float tot[2];
    #pragma unroll
    for (int ni = 0; ni < 2; ++ni) {
        float t = lsum[ni];
        t += __shfl_xor(t, 16, 64);
        t += __shfl_xor(t, 32, 64);
        tot[ni] = t;
    }

    if (direct) {
        const int b = bh >> 3, h = bh & 7;
        #pragma unroll
        for (int ni = 0; ni < 2; ++ni) {
            const float inv = 1.f / tot[ni];
            const int qi = q0 + wv * 32 + ni * 16 + l16;
            ushort* dst = att + ((size_t)(b * S_LEN + qi)) * DMODEL + h * DHEAD;
            #pragma unroll
            for (int mi = 0; mi < 4; ++mi) {
                uint2 o;
                o.x = pk2(oacc[mi][ni][0] * inv, oacc[mi][ni][1] * inv);
                o.y = pk2(oacc[mi][ni][2] * inv, oacc[mi][ni][3] * inv);
                *(uint2*)(dst + mi * 16 + quad * 4) = o;
            }
        }
    } else {
        #pragma unroll
        for (int ni = 0; ni < 2; ++ni) {
            const int qi = q0 + wv * 32 + ni * 16 + l16;
            const size_t row = (size_t)(ck * 32 + bh) * S_LEN + qi;
            if (quad == 0) Lpart[row] = tot[ni];
            #pragma unroll
            for (int mi = 0; mi < 4; ++mi) {
                float4 o = { oacc[mi][ni][0], oacc[mi][ni][1],
                             oacc[mi][ni][2], oacc[mi][ni][3] };
                *(float4*)&Opart[row * DHEAD + mi * 16 + quad * 4] = o;
            }
        }
    }
}

// ---------------------------------------------------------------------------
// Kernel 2b: combine split-S partials -> bf16 att (SPLIT==2 only).
// ---------------------------------------------------------------------------
__global__ __launch_bounds__(256) void combine(
    const float* __restrict__ Opart, const float* __restrict__ Lpart,
    ushort* __restrict__ att)
{
    const int idx = blockIdx.x * 256 + threadIdx.x;
    const int row = idx >> 3;
    const int dho = (idx & 7) * 8;
    const int bh = row >> 11, qq = row & 2047;
    const float* o0 = Opart + (size_t)row * DHEAD + dho;
    const float* o1 = Opart + (size_t)(65536 + row) * DHEAD + dho;
    float4 a0 = *(const float4*)o0,       a1 = *(const float4*)(o0 + 4);
    float4 b0 = *(const float4*)o1,       b1 = *(const float4*)(o1 + 4);
    const float inv = 1.f / (Lpart[row] + Lpart[65536 + row]);
    uint4 u;
    u.x = pk2((a0.x + b0.x) * inv, (a0.y + b0.y) * inv);
    u.y = pk2((a0.z + b0.z) * inv, (a0.w + b0.w) * inv);
    u.z = pk2((a1.x + b1.x) * inv, (a1.y + b1.y) * inv);
    u.w = pk2((a1.z + b1.z) * inv, (a1.w + b1.w) * inv);
    ushort* dst = att + ((size_t)((bh >> 3) * S_LEN + qq)) * DMODEL + (bh & 7) * DHEAD + dho;
    *(uint4*)dst = u;
}

// ---------------------------------------------------------------------------
// Kernel 3: output projection, same DMA staging; out fp32.
// ---------------------------------------------------------------------------
__global__ __launch_bounds__(256) void out_gemm(
    const ushort* __restrict__ att, const ushort* __restrict__ WoT,
    const float* __restrict__ bo, float* __restrict__ out)
{
    __shared__ ushort SMEM[8192];  // As 8KB + Bs 8KB
    ushort* As = SMEM;
    ushort* Bs = SMEM + 4096;

    const int tid = threadIdx.x;
    const int wv  = tid >> 6, lane = tid & 63, l16 = lane & 15, quad = lane >> 4;
    const int m0 = blockIdx.x * 128;
    const int n0 = blockIdx.y * 128;

    const int wm = (wv & 1) * 64, wn = (wv >> 1) * 64;
    floatx4 acc[4][4] = {};

    for (int k0 = 0; k0 < DMODEL; k0 += 32) {
        #pragma unroll
        for (int c = 0; c < 2; ++c) {
            const int g64 = wv * 2 + c;
            const int qk  = g64 >> 1;
            const int row = ((g64 & 1) << 6) + lane;
            gload16(att + (size_t)(m0 + row) * DMODEL + k0 + qk * 8, As + g64 * 512);
            gload16(WoT + (size_t)(n0 + row) * DMODEL + k0 + qk * 8, Bs + g64 * 512);
        }
        __syncthreads();

        short8 af[4], bf[4];
        #pragma unroll
        for (int i = 0; i < 4; ++i)
            af[i] = *(const short8*)(As + (size_t)(quad * 128 + wm + i * 16 + l16) * 8);
        #pragma unroll
        for (int c = 0; c < 4; ++c)
            bf[c] = *(const short8*)(Bs + (size_t)(quad * 128 + wn + c * 16 + l16) * 8);
        #pragma unroll
        for (int i = 0; i < 4; ++i)
            #pragma unroll
            for (int c = 0; c < 4; ++c)
                acc[i][c] = __builtin_amdgcn_mfma_f32_16x16x32_bf16(af[i], bf[c], acc[i][c], 0, 0, 0);
        __syncthreads();
    }

    #pragma unroll
    for (int c = 0; c < 4; ++c) {
        const int n = n0 + wn + c * 16 + l16;
        const float bb = bo[n];
        #pragma unroll
        for (int i = 0; i < 4; ++i)
            #pragma unroll
            for (int r = 0; r < 4; ++r) {
                const int m = m0 + wm + i * 16 + quad * 4 + r;
                out[(size_t)m * DMODEL + n] = acc[i][c][r] + bb;
            }
    }
}

// ---------------------------------------------------------------------------
extern "C" void kernel_launch(void* const* d_in, const int* in_sizes, int n_in,
                              void* d_out, int out_size, void* d_ws, size_t ws_size,
                              hipStream_t stream)
{
    const float* x  = (const float*)d_in[0];
    const float* Wq = (const float*)d_in[1];
    const float* bq = (const float*)d_in[2];
    const float* Wk = (const float*)d_in[3];
    const float* bk = (const float*)d_in[4];
    const float* Wv = (const float*)d_in[5];
    const float* bv = (const float*)d_in[6];
    const float* Wo = (const float*)d_in[7];
    const float* bo = (const float*)d_in[8];
    float* out = (float*)d_out;

    ushort* ws = (ushort*)d_ws;
    const size_t SZ = (size_t)M_TOT * DMODEL;
    ushort* xb  = ws;            // aliased by att after qkv consumes xb
    ushort* att = ws;
    ushort* WT  = ws + SZ;
    ushort* q   = WT + 4 * (size_t)DMODEL * DMODEL;
    ushort* k   = q + SZ;
    ushort* vT  = k + SZ;
    float*  Opart = (float*)(vT + SZ);
    float*  Lpart = Opart + 2 * (size_t)32 * S_LEN * DHEAD;

    const size_t base_need  = (size_t)(vT + SZ - ws) * 2;
    const size_t split_need = base_need + 2 * ((size_t)32 * S_LEN * DHEAD + 32 * S_LEN) * 4;
    const int SPLIT = (ws_size >= split_need) ? 2 : 1;

    prep<<<4096 + 256, 256, 0, stream>>>(x, Wq, Wk, Wv, Wo, xb, WT);

    qkv_gemm<<<dim3(M_TOT / 128, 3 * DMODEL / 128), 256, 0, stream>>>(
        xb, WT, bq, bk, bv, q, k, vT);

    attn<<<dim3(S_LEN / 128, BATCH * NHEADS, SPLIT), 256, 0, stream>>>(
        q, k, vT, att, Opart, Lpart, S_LEN / 64 / SPLIT, SPLIT == 1 ? 1 : 0);

    if (SPLIT == 2)
        combine<<<(32 * S_LEN * DHEAD / 8) / 256, 256, 0, stream>>>(Opart, Lpart, att);

    out_gemm<<<dim3(M_TOT / 128, DMODEL / 128), 256, 0, stream>>>(
        att, WT + 3 * (size_t)DMODEL * DMODEL, bo, out);
}

// Round 8
// 177.493 us; speedup vs baseline: 1.1192x; 1.1192x over previous
//
#include <hip/hip_runtime.h>
#include <math.h>

#define BATCH   4
#define S_LEN   2048
#define DMODEL  512
#define NHEADS  8
#define DHEAD   64
#define M_TOT   8192
#define ATT_SCALE 0.04419417382415922f   // 1/sqrt(512)
#define QSCALE (ATT_SCALE * 1.44269504088896f)  // fold log2(e): exp2 in softmax

using short8  = __attribute__((ext_vector_type(8))) short;
using short4v = __attribute__((ext_vector_type(4))) short;
using floatx4 = __attribute__((ext_vector_type(4))) float;

// fp32 -> bf16 RNE
__device__ __forceinline__ ushort f2bf(float f) {
    union { float f; unsigned u; } x; x.f = f;
    unsigned u = x.u + 0x7FFFu + ((x.u >> 16) & 1u);
    return (ushort)(u >> 16);
}
__device__ __forceinline__ unsigned pk2(float a, float b) {
    return (unsigned)f2bf(a) | ((unsigned)f2bf(b) << 16);
}
// fp32x2 -> packed bf16x2, round-half-up — hot-loop use
__device__ __forceinline__ unsigned pkr2(float a, float b) {
    unsigned ua = __float_as_uint(a) + 0x8000u;
    unsigned ub = __float_as_uint(b) + 0x8000u;
    return __builtin_amdgcn_perm(ub, ua, 0x07060302u);
}

// ---------------------------------------------------------------------------
// Preprocess: blocks [0,4096) x fp32->bf16; [4096,4352) W transpose to bf16.
// ---------------------------------------------------------------------------
__global__ __launch_bounds__(256) void prep(
    const float* __restrict__ x,
    const float* __restrict__ Wq, const float* __restrict__ Wk,
    const float* __restrict__ Wv, const float* __restrict__ Wo,
    ushort* __restrict__ xb, ushort* __restrict__ WT)
{
    const int bid = blockIdx.x;
    if (bid < 4096) {
        const int i = (bid * 256 + threadIdx.x) * 4;
        float4 f = *(const float4*)(x + i);
        uint2 o; o.x = pk2(f.x, f.y); o.y = pk2(f.z, f.w);
        *(uint2*)(xb + i) = o;
    } else {
        const int rb = bid - 4096;
        const int p  = rb >> 6;
        const int rem = rb & 63;
        const int n  = (rem >> 5) * 256 + threadIdx.x;
        const int k0 = (rem & 31) * 16;
        const float* W = (p == 0) ? Wq : (p == 1) ? Wk : (p == 2) ? Wv : Wo;
        unsigned u[8];
        #pragma unroll
        for (int j = 0; j < 8; ++j) {
            float a = W[(k0 + 2 * j)     * DMODEL + n];
            float b = W[(k0 + 2 * j + 1) * DMODEL + n];
            u[j] = pk2(a, b);
        }
        ushort* dst = WT + ((size_t)p * DMODEL + n) * DMODEL + k0;
        *(uint4*)dst       = *(uint4*)&u[0];
        *(uint4*)(dst + 8) = *(uint4*)&u[4];
    }
}

// ---------------------------------------------------------------------------
// Kernel 1: fused QKV projection, 128x128 tile, BK=32 (round-6 VGPR staging
// + register prefetch of next tile).  Q pre-scaled by QSCALE; V exits via
// LDS transpose -> coalesced [B,H,Dh,S] b128 stores.
// ---------------------------------------------------------------------------
__global__ __launch_bounds__(256, 4) void qkv_gemm(
    const ushort* __restrict__ xb, const ushort* __restrict__ WT,
    const float* __restrict__ bq, const float* __restrict__ bk, const float* __restrict__ bv,
    ushort* __restrict__ q, ushort* __restrict__ k, ushort* __restrict__ vT)
{
    __shared__ ushort SMEM[128 * 136];   // K-loop A+B (20.5 KB); CT overlay
    ushort (*A)[40] = (ushort(*)[40])SMEM;
    ushort (*B)[40] = (ushort(*)[40])(SMEM + 128 * 40);
    ushort (*CT)[136] = (ushort(*)[136])SMEM;

    const int tid = threadIdx.x;
    const int wv  = tid >> 6, lane = tid & 63, l16 = lane & 15, quad = lane >> 4;
    const int m0  = blockIdx.x * 128;
    const int ng0 = blockIdx.y * 128;
    const int p   = ng0 >> 9;
    const int n0  = ng0 & 511;
    const ushort* Wp  = WT + (size_t)p * DMODEL * DMODEL + (size_t)n0 * DMODEL;
    const float* bias = (p == 0) ? bq : (p == 1) ? bk : bv;
    const float scl   = (p == 0) ? QSCALE : 1.0f;

    const int wm = (wv & 1) * 64, wn = (wv >> 1) * 64;
    floatx4 acc[4][4] = {};
    const int ar = tid >> 1, ac = (tid & 1) * 16;

    uint4 pa0, pa1, pb0, pb1;
    pa0 = *(const uint4*)(xb + (size_t)(m0 + ar) * DMODEL + ac);
    pa1 = *(const uint4*)(xb + (size_t)(m0 + ar) * DMODEL + ac + 8);
    pb0 = *(const uint4*)(Wp + (size_t)ar * DMODEL + ac);
    pb1 = *(const uint4*)(Wp + (size_t)ar * DMODEL + ac + 8);

    for (int k0 = 0; k0 < DMODEL; k0 += 32) {
        *(uint4*)&A[ar][ac] = pa0; *(uint4*)&A[ar][ac + 8] = pa1;
        *(uint4*)&B[ar][ac] = pb0; *(uint4*)&B[ar][ac + 8] = pb1;
        __syncthreads();

        if (k0 + 32 < DMODEL) {
            pa0 = *(const uint4*)(xb + (size_t)(m0 + ar) * DMODEL + k0 + 32 + ac);
            pa1 = *(const uint4*)(xb + (size_t)(m0 + ar) * DMODEL + k0 + 32 + ac + 8);
            pb0 = *(const uint4*)(Wp + (size_t)ar * DMODEL + k0 + 32 + ac);
            pb1 = *(const uint4*)(Wp + (size_t)ar * DMODEL + k0 + 32 + ac + 8);
        }

        short8 af[4], bf[4];
        #pragma unroll
        for (int i = 0; i < 4; ++i) af[i] = *(const short8*)&A[wm + i * 16 + l16][quad * 8];
        #pragma unroll
        for (int c = 0; c < 4; ++c) bf[c] = *(const short8*)&B[wn + c * 16 + l16][quad * 8];
        #pragma unroll
        for (int i = 0; i < 4; ++i)
            #pragma unroll
            for (int c = 0; c < 4; ++c)
                acc[i][c] = __builtin_amdgcn_mfma_f32_16x16x32_bf16(af[i], bf[c], acc[i][c], 0, 0, 0);
        __syncthreads();
    }

    if (p < 2) {
        #pragma unroll
        for (int c = 0; c < 4; ++c) {
            const int n = n0 + wn + c * 16 + l16;
            const float bb = bias[n];
            const int h = n >> 6, dh = n & 63;
            #pragma unroll
            for (int i = 0; i < 4; ++i)
                #pragma unroll
                for (int r = 0; r < 4; ++r) {
                    const int m = m0 + wm + i * 16 + quad * 4 + r;
                    const int b = m >> 11, s = m & 2047;
                    const ushort val = f2bf((acc[i][c][r] + bb) * scl);
                    if (p == 0) q[((size_t)(b * NHEADS + h) * S_LEN + s) * DHEAD + dh] = val;
                    else        k[((size_t)(b * NHEADS + h) * S_LEN + s) * DHEAD + dh] = val;
                }
        }
    } else {
        #pragma unroll
        for (int c = 0; c < 4; ++c) {
            const int n = wn + c * 16 + l16;
            const float bb = bias[n0 + n];
            #pragma unroll
            for (int i = 0; i < 4; ++i) {
                uint2 o;
                o.x = pk2(acc[i][c][0] + bb, acc[i][c][1] + bb);
                o.y = pk2(acc[i][c][2] + bb, acc[i][c][3] + bb);
                *(uint2*)&CT[n][wm + i * 16 + quad * 4] = o;
            }
        }
        __syncthreads();
        const int n  = tid >> 1, mh = (tid & 1) * 64;
        const int gn = n0 + n;
        const int h  = gn >> 6, dh = gn & 63;
        const int b  = m0 >> 11, sb = (m0 & 2047) + mh;
        ushort* dst = vT + ((size_t)(b * NHEADS + h) * DHEAD + dh) * S_LEN + sb;
        #pragma unroll
        for (int j = 0; j < 8; ++j)
            *(uint4*)(dst + j * 8) = *(const uint4*)&CT[n][mh + j * 8];
    }
}

// ---------------------------------------------------------------------------
// Kernel 2: flash attention, S^T = K·Q^T, split-S over blockIdx.z.
// PV now feeds MFMA DIRECTLY from registers: S^T C-layout (4 consecutive
// keys/lane = quad*4+r) matches the K=16 MFMA B-fragment (k=quad*4+j), so
// O^T += V^T·P^T uses mfma_f32_16x16x16bf16_1k with pf from the exp/pack
// regs — no P LDS round-trip.  K/V double-buffered, ONE barrier per iter.
// ---------------------------------------------------------------------------
__global__ __launch_bounds__(256, 4) void attn(
    const ushort* __restrict__ Q, const ushort* __restrict__ K,
    const ushort* __restrict__ vT,
    float* __restrict__ Opart, float* __restrict__ Lpart, const int KT)
{
    __shared__ ushort Klds[2][64][72];
    __shared__ ushort Vt[2][64][72];

    const int tid = threadIdx.x;
    const int wv  = tid >> 6, lane = tid & 63, l16 = lane & 15, quad = lane >> 4;
    const int q0  = blockIdx.x * 128;
    const int bh  = blockIdx.y;
    const int ck  = blockIdx.z;
    const int kbase = ck * KT;
    const ushort* Qh = Q  + (size_t)bh * S_LEN * DHEAD;
    const ushort* Kh = K  + (size_t)bh * S_LEN * DHEAD;
    const ushort* Vh = vT + (size_t)bh * DHEAD * S_LEN;

    short8 qf[2][2];
    #pragma unroll
    for (int ni = 0; ni < 2; ++ni) {
        const ushort* qrow = Qh + (size_t)(q0 + wv * 32 + ni * 16 + l16) * DHEAD;
        qf[0][ni] = *(const short8*)(qrow + quad * 8);
        qf[1][ni] = *(const short8*)(qrow + 32 + quad * 8);
    }

    floatx4 oacc[4][2] = {};   // O^T: [dh-tile][q-tile]
    float lsum[2] = {0.f, 0.f};

    const int srow = tid >> 2, sc0 = (tid & 3) * 16;
    uint4 ka, kb, va, vb;
    {
        const ushort* Ks = Kh + (size_t)(kbase * 64 + srow) * DHEAD + sc0;
        const ushort* Vs = Vh + (size_t)srow * S_LEN + kbase * 64 + sc0;
        ka = *(const uint4*)Ks; kb = *(const uint4*)(Ks + 8);
        va = *(const uint4*)Vs; vb = *(const uint4*)(Vs + 8);
    }

    for (int kt = 0; kt < KT; ++kt) {
        const int buf = kt & 1;
        *(uint4*)&Klds[buf][srow][sc0] = ka; *(uint4*)&Klds[buf][srow][sc0 + 8] = kb;
        *(uint4*)&Vt[buf][srow][sc0]   = va; *(uint4*)&Vt[buf][srow][sc0 + 8]   = vb;
        __syncthreads();   // sole barrier: dbuf makes the tail barrier unnecessary

        if (kt + 1 < KT) {
            const ushort* Ks = Kh + (size_t)((kbase + kt + 1) * 64 + srow) * DHEAD + sc0;
            const ushort* Vs = Vh + (size_t)srow * S_LEN + (kbase + kt + 1) * 64 + sc0;
            ka = *(const uint4*)Ks; kb = *(const uint4*)(Ks + 8);
            va = *(const uint4*)Vs; vb = *(const uint4*)(Vs + 8);
        }

        #pragma unroll
        for (int mi = 0; mi < 4; ++mi) {
            // S^T for this 16-key block: lane = (key quad*4+r, q l16)
            floatx4 s0 = {}, s1 = {};
            #pragma unroll
            for (int s = 0; s < 2; ++s) {
                short8 kf = *(const short8*)&Klds[buf][mi * 16 + l16][s * 32 + quad * 8];
                s0 = __builtin_amdgcn_mfma_f32_16x16x32_bf16(kf, qf[s][0], s0, 0, 0, 0);
                s1 = __builtin_amdgcn_mfma_f32_16x16x32_bf16(kf, qf[s][1], s1, 0, 0, 0);
            }
            // V^T A-fragments for the K=16 PV MFMA: A[m=dh=c*16+l16][k=quad*4+j]
            short4v vfr[4];
            #pragma unroll
            for (int c = 0; c < 4; ++c)
                vfr[c] = *(const short4v*)&Vt[buf][c * 16 + l16][mi * 16 + quad * 4];

            // ni = 0
            {
                const float p0 = __builtin_amdgcn_exp2f(s0[0]);
                const float p1 = __builtin_amdgcn_exp2f(s0[1]);
                const float p2 = __builtin_amdgcn_exp2f(s0[2]);
                const float p3 = __builtin_amdgcn_exp2f(s0[3]);
                lsum[0] += (p0 + p1) + (p2 + p3);
                uint2 o; o.x = pkr2(p0, p1); o.y = pkr2(p2, p3);
                short4v pf; *(uint2*)&pf = o;   // keys quad*4+{0..3}, q=l16
                #pragma unroll
                for (int c = 0; c < 4; ++c)
                    oacc[c][0] = __builtin_amdgcn_mfma_f32_16x16x16bf16_1k(vfr[c], pf, oacc[c][0], 0, 0, 0);
            }
            // ni = 1
            {
                const float p0 = __builtin_amdgcn_exp2f(s1[0]);
                const float p1 = __builtin_amdgcn_exp2f(s1[1]);
                const float p2 = __builtin_amdgcn_exp2f(s1[2]);
                const float p3 = __builtin_amdgcn_exp2f(s1[3]);
                lsum[1] += (p0 + p1) + (p2 + p3);
                uint2 o; o.x = pkr2(p0, p1); o.y = pkr2(p2, p3);
                short4v pf; *(uint2*)&pf = o;
                #pragma unroll
                for (int c = 0; c < 4; ++c)
                    oacc[c][1] = __builtin_amdgcn_mfma_f32_16x16x16bf16_1k(vfr[c], pf, oacc[c][1], 0, 0, 0);
            }
        }
    }

    float tot[2];
    #pragma unroll
    for (int ni = 0; ni < 2; ++ni) {
        float t = lsum[ni];
        t += __shfl_xor(t, 16, 64);
        t += __shfl_xor(t, 32, 64);
        tot[ni] = t;
    }

    // partials: row = (ck*32+bh)*2048 + qi
    #pragma unroll
    for (int ni = 0; ni < 2; ++ni) {
        const int qi = q0 + wv * 32 + ni * 16 + l16;
        const size_t row = (size_t)(ck * 32 + bh) * S_LEN + qi;
        if (quad == 0) Lpart[row] = tot[ni];
        #pragma unroll
        for (int mi = 0; mi < 4; ++mi) {
            float4 o = { oacc[mi][ni][0], oacc[mi][ni][1],
                         oacc[mi][ni][2], oacc[mi][ni][3] };
            *(float4*)&Opart[row * DHEAD + mi * 16 + quad * 4] = o;
        }
    }
}

// ---------------------------------------------------------------------------
// Kernel 3: output projection FUSED with split-S combine.  A-tile staged
// directly from fp32 partials: a[m][k] = (O0+O1)*inv(L0+L1), k = h*64+dh.
// Tile 64(M)x128(N) -> 512 blocks (2/CU).  out fp32.
// ---------------------------------------------------------------------------
__global__ __launch_bounds__(256, 4) void out_gemm(
    const float* __restrict__ Opart, const float* __restrict__ Lpart,
    const ushort* __restrict__ WoT, const float* __restrict__ bo,
    float* __restrict__ out)
{
    __shared__ ushort A[64][40];
    __shared__ ushort B[128][40];

    const int tid = threadIdx.x;
    const int wv  = tid >> 6, lane = tid & 63, l16 = lane & 15, quad = lane >> 4;
    const int m0 = blockIdx.x * 64;
    const int n0 = blockIdx.y * 128;

    // A staging: 64 rows x 32 k, 8 elems/thread
    const int ar = tid >> 2, ac = (tid & 3) * 8;
    const int am = m0 + ar, ab = am >> 11, aq = am & 2047;
    // per-thread row-invariant: inv l for all 8 heads
    float invl[NHEADS];
    #pragma unroll
    for (int h = 0; h < NHEADS; ++h) {
        const size_t rw = (size_t)(ab * NHEADS + h) * S_LEN + aq;
        invl[h] = 1.f / (Lpart[rw] + Lpart[65536 + rw]);
    }
    // B staging: 128 rows x 32 k, 16 elems/thread
    const int br = tid >> 1, bc = (tid & 1) * 16;

    floatx4 acc[8] = {};

    for (int k0 = 0; k0 < DMODEL; k0 += 32) {
        const int kk = k0 + ac, h = kk >> 6, dh = kk & 63;
        const float* p0 = Opart + ((size_t)(ab * NHEADS + h) * S_LEN + aq) * DHEAD + dh;
        const float* p1 = p0 + (size_t)65536 * DHEAD;
        float4 a0 = *(const float4*)p0,       a1 = *(const float4*)(p0 + 4);
        float4 c0 = *(const float4*)p1,       c1 = *(const float4*)(p1 + 4);
        const float iv = invl[h];
        uint2 u0, u1;
        u0.x = pk2((a0.x + c0.x) * iv, (a0.y + c0.y) * iv);
        u0.y = pk2((a0.z + c0.z) * iv, (a0.w + c0.w) * iv);
        u1.x = pk2((a1.x + c1.x) * iv, (a1.y + c1.y) * iv);
        u1.y = pk2((a1.z + c1.z) * iv, (a1.w + c1.w) * iv);
        *(uint2*)&A[ar][ac]     = u0;
        *(uint2*)&A[ar][ac + 4] = u1;

        uint4 b0 = *(const uint4*)(WoT + (size_t)(n0 + br) * DMODEL + k0 + bc);
        uint4 b1 = *(const uint4*)(WoT + (size_t)(n0 + br) * DMODEL + k0 + bc + 8);
        *(uint4*)&B[br][bc] = b0; *(uint4*)&B[br][bc + 8] = b1;
        __syncthreads();

        short8 af = *(const short8*)&A[wv * 16 + l16][quad * 8];
        #pragma unroll
        for (int c = 0; c < 8; ++c) {
            short8 bf = *(const short8*)&B[c * 16 + l16][quad * 8];
            acc[c] = __builtin_amdgcn_mfma_f32_16x16x32_bf16(af, bf, acc[c], 0, 0, 0);
        }
        __syncthreads();
    }

    #pragma unroll
    for (int c = 0; c < 8; ++c) {
        const int n = n0 + c * 16 + l16;
        const float bb = bo[n];
        #pragma unroll
        for (int r = 0; r < 4; ++r) {
            const int m = m0 + wv * 16 + quad * 4 + r;
            out[(size_t)m * DMODEL + n] = acc[c][r] + bb;
        }
    }
}

// ---------------------------------------------------------------------------
extern "C" void kernel_launch(void* const* d_in, const int* in_sizes, int n_in,
                              void* d_out, int out_size, void* d_ws, size_t ws_size,
                              hipStream_t stream)
{
    const float* x  = (const float*)d_in[0];
    const float* Wq = (const float*)d_in[1];
    const float* bq = (const float*)d_in[2];
    const float* Wk = (const float*)d_in[3];
    const float* bk = (const float*)d_in[4];
    const float* Wv = (const float*)d_in[5];
    const float* bv = (const float*)d_in[6];
    const float* Wo = (const float*)d_in[7];
    const float* bo = (const float*)d_in[8];
    float* out = (float*)d_out;

    ushort* ws = (ushort*)d_ws;
    const size_t SZ = (size_t)M_TOT * DMODEL;
    ushort* xb  = ws;
    ushort* WT  = ws + SZ;
    ushort* q   = WT + 4 * (size_t)DMODEL * DMODEL;
    ushort* k   = q + SZ;
    ushort* vT  = k + SZ;
    float*  Opart = (float*)(vT + SZ);                        // 2 x 32 x 2048 x 64 fp32
    float*  Lpart = Opart + 2 * (size_t)32 * S_LEN * DHEAD;   // 2 x 32 x 2048 fp32

    prep<<<4096 + 256, 256, 0, stream>>>(x, Wq, Wk, Wv, Wo, xb, WT);

    qkv_gemm<<<dim3(M_TOT / 128, 3 * DMODEL / 128), 256, 0, stream>>>(
        xb, WT, bq, bk, bv, q, k, vT);

    attn<<<dim3(S_LEN / 128, BATCH * NHEADS, 2), 256, 0, stream>>>(
        q, k, vT, Opart, Lpart, S_LEN / 64 / 2);

    out_gemm<<<dim3(M_TOT / 64, DMODEL / 128), 256, 0, stream>>>(
        Opart, Lpart, WT + 3 * (size_t)DMODEL * DMODEL, bo, out);
}